// Round 2
// baseline (1436.590 us; speedup 1.0000x reference)
//
#include <hip/hip_runtime.h>

// GraphConvolution: out = segment_sum(edge_val * (x@W)[edge_col], edge_row) + b
// M=100000 nodes, K=256 in_feats, N=128 out_feats, E=1.6M edges. fp32 in/out.
//
// R6: kill the row-granularity sort. R5 spent two kernels (bucket_scan +
// bucket_to_sorted) turning 128-row buckets into a fully row-sorted edge list
// so spmm could be wave-per-row atomic-free — but spmm was latency-bound
// anyway (31% VALU, 29% HBM, 2-deep dependent gather chain per wave).
// Now: partition to 64-row buckets, then one block per bucket accumulates
// straight into a 32KB LDS fp32 tile (64 rows x 128 feats) via ds_add_f32,
// wave-per-edge with 16-deep gather unroll (16 independent 256B gathers in
// flight per wave vs 2 before). bucket_scan/bucket_to_sorted/off0/sedge gone.
// R7: fix compile error — __builtin_nontemporal_store needs a native vector
// type, not HIP_vector_type<float,4>. Epilogue now uses float4v throughout.

#define K_FEATS 256
#define N_FEATS 128
#define BSHIFT 6                 // 64 rows per bucket
#define BROWS 64
#define BCAP 1792                // mean 1024, sigma 32 -> +24 sigma
#define NBPAD 2048               // LDS hist capacity (NB = 1563)
#define CHUNK 8192
#define EPT 32                   // edges per thread (256 threads)

typedef __attribute__((ext_vector_type(8))) short short8;
typedef __attribute__((ext_vector_type(4))) float float4v;

__device__ __forceinline__ unsigned short f2bf(float f) {
    unsigned int u = __float_as_uint(f);
    unsigned int r = u + 0x7FFF + ((u >> 16) & 1);   // round-to-nearest-even
    return (unsigned short)(r >> 16);
}

// ---------------- prep: Wt[n][k] bf16 from w[k][n] fp32 ----------------
__global__ __launch_bounds__(256) void prep_w(const float* __restrict__ w,
                                              unsigned short* __restrict__ wt) {
    int n = blockIdx.x;
    int k = threadIdx.x;
    wt[n * K_FEATS + k] = f2bf(w[k * N_FEATS + n]);
}

// ---------------- GEMM: sup(bf16) = x @ W via MFMA ----------------
__global__ __launch_bounds__(256) void gcn_gemm_mfma(const float* __restrict__ x,
                                                     const unsigned short* __restrict__ wt,
                                                     unsigned short* __restrict__ sup, int M) {
    __shared__ __align__(16) unsigned short As[128 * 40];

    const int tid  = threadIdx.x;
    const int wv   = tid >> 6;
    const int lane = tid & 63;
    const int l15  = lane & 15;
    const int quad = lane >> 4;
    const int row0 = blockIdx.x * 128;

    float4v acc[2][8];
#pragma unroll
    for (int mt = 0; mt < 2; mt++)
#pragma unroll
        for (int nt = 0; nt < 8; nt++) acc[mt][nt] = (float4v)(0.f);

    for (int k0 = 0; k0 < K_FEATS; k0 += 32) {
#pragma unroll
        for (int l = 0; l < 4; l++) {
            int f   = tid + l * 256;
            int r   = f >> 3;
            int k4  = f & 7;
            int grow = row0 + r;
            float4 v = make_float4(0.f, 0.f, 0.f, 0.f);
            if (grow < M) v = *(const float4*)(x + (long)grow * K_FEATS + k0 + k4 * 4);
            unsigned int p0 = (unsigned int)f2bf(v.x) | ((unsigned int)f2bf(v.y) << 16);
            unsigned int p1 = (unsigned int)f2bf(v.z) | ((unsigned int)f2bf(v.w) << 16);
            *(uint2*)(&As[r * 40 + k4 * 4]) = make_uint2(p0, p1);
        }
        __syncthreads();

        short8 afrag[2];
#pragma unroll
        for (int mt = 0; mt < 2; mt++) {
            afrag[mt] = *(const short8*)(&As[(wv * 32 + mt * 16 + l15) * 40 + quad * 8]);
        }
        short8 bfrag[8];
#pragma unroll
        for (int nt = 0; nt < 8; nt++) {
            bfrag[nt] = *(const short8*)(wt + (nt * 16 + l15) * K_FEATS + k0 + quad * 8);
        }
#pragma unroll
        for (int mt = 0; mt < 2; mt++)
#pragma unroll
            for (int nt = 0; nt < 8; nt++)
                acc[mt][nt] = __builtin_amdgcn_mfma_f32_16x16x32_bf16(
                    afrag[mt], bfrag[nt], acc[mt][nt], 0, 0, 0);
        __syncthreads();
    }

#pragma unroll
    for (int mt = 0; mt < 2; mt++) {
#pragma unroll
        for (int reg = 0; reg < 4; reg++) {
            int grow = row0 + wv * 32 + mt * 16 + quad * 4 + reg;
            if (grow < M) {
#pragma unroll
                for (int nt = 0; nt < 8; nt++) {
                    sup[(long)grow * N_FEATS + nt * 16 + l15] = f2bf(acc[mt][nt][reg]);
                }
            }
        }
    }
}

// ---------------- bucket partition ----------------
__global__ __launch_bounds__(256) void zero_ints(int* __restrict__ p, int n) {
    int i = blockIdx.x * 256 + threadIdx.x;
    if (i < n) p[i] = 0;
}

// Per-chunk LDS histogram -> one reservation atomic per (WG,bucket)
// -> write edges in runs inside bucket-strided tmp regions.
__global__ __launch_bounds__(256) void wg_partition(const int* __restrict__ erow,
                                                    const int* __restrict__ ecol,
                                                    const float* __restrict__ eval_,
                                                    int* __restrict__ bcur,
                                                    int2* __restrict__ tmp, int E, int NB) {
    __shared__ int hist[NBPAD];
    __shared__ int cur[NBPAD];
    const int tid = threadIdx.x;
    const long e0 = (long)blockIdx.x * CHUNK;

    for (int i = tid; i < NB; i += 256) hist[i] = 0;
    __syncthreads();

    int rows[EPT];
#pragma unroll
    for (int i = 0; i < EPT; i++) {
        long e = e0 + tid + i * 256;
        int r = -1;
        if (e < E) {
            r = erow[e];
            atomicAdd(&hist[r >> BSHIFT], 1);
        }
        rows[i] = r;
    }
    __syncthreads();

    // one global reservation per touched bucket
    for (int i = tid; i < NB; i += 256) {
        int c = hist[i];
        cur[i] = c ? atomicAdd(&bcur[i], c) : 0;
    }
    __syncthreads();

    // place edges: LDS cursor gives offset within this WG's reserved run
#pragma unroll
    for (int i = 0; i < EPT; i++) {
        long e = e0 + tid + i * 256;
        if (e >= E) continue;
        int r = rows[i];
        int b = r >> BSHIFT;
        int p = atomicAdd(&cur[b], 1);
        if (p < BCAP)
            tmp[(long)b * BCAP + p] = make_int2(((r & (BROWS - 1)) << 17) | ecol[e],
                                                __float_as_int(eval_[e]));
    }
}

// ---------------- SpMM: block per bucket, LDS fp32 accumulator ----------------
// 64 rows x 128 feats x 4B = 32KB LDS -> 5 blocks/CU. Wave-per-edge,
// 16-deep gather unroll, ds_add_f32 accumulation (2-way bank alias = free).
__global__ __launch_bounds__(256) void gcn_spmm_bucket(const int* __restrict__ bcur,
                                                       const int2* __restrict__ tmp,
                                                       const unsigned int* __restrict__ sup32,
                                                       const float* __restrict__ b,
                                                       float* __restrict__ out, int M) {
    __shared__ float acc[BROWS * N_FEATS];   // 32 KB
    const int bkt  = blockIdx.x;
    const int tid  = threadIdx.x;
    const int wv   = tid >> 6;
    const int lane = tid & 63;

    for (int i = tid; i < BROWS * N_FEATS; i += 256) acc[i] = 0.f;
    __syncthreads();

    int cnt = bcur[bkt];
    if (cnt > BCAP) cnt = BCAP;
    const int2* t = tmp + (long)bkt * BCAP;

    const int full = cnt & ~63;              // 4 waves x 16 edges per pass
    for (int i = wv * 16; i < full; i += 64) {
        int2 em[16];
#pragma unroll
        for (int u = 0; u < 16; u++) em[u] = t[i + u];
        unsigned int g[16];
#pragma unroll
        for (int u = 0; u < 16; u++) {
            unsigned int off = ((unsigned)(em[u].x & 0x1FFFF) << 6) + lane;
            g[u] = sup32[off];
        }
#pragma unroll
        for (int u = 0; u < 16; u++) {
            float v  = __int_as_float(em[u].y);
            int   rl = (unsigned)em[u].x >> 17;
            atomicAdd(&acc[rl * N_FEATS + lane * 2],     v * __uint_as_float(g[u] << 16));
            atomicAdd(&acc[rl * N_FEATS + lane * 2 + 1], v * __uint_as_float(g[u] & 0xFFFF0000u));
        }
    }
    // tail (< 64 edges), one edge per wave per step
    for (int i = full + wv; i < cnt; i += 4) {
        int2 em = t[i];
        unsigned int g = sup32[((unsigned)(em.x & 0x1FFFF) << 6) + lane];
        float v  = __int_as_float(em.y);
        int   rl = (unsigned)em.x >> 17;
        atomicAdd(&acc[rl * N_FEATS + lane * 2],     v * __uint_as_float(g << 16));
        atomicAdd(&acc[rl * N_FEATS + lane * 2 + 1], v * __uint_as_float(g & 0xFFFF0000u));
    }
    __syncthreads();

    const int row0 = bkt << BSHIFT;
    for (int i = tid; i < BROWS * 32; i += 256) {
        int r    = i >> 5;
        int c4   = i & 31;
        int grow = row0 + r;
        if (grow >= M) continue;
        float4v a  = *(const float4v*)&acc[r * N_FEATS + c4 * 4];
        float4v bb = ((const float4v*)b)[c4];
        a += bb;
        __builtin_nontemporal_store(a, (float4v*)(out + (long)grow * N_FEATS + c4 * 4));
    }
}

extern "C" void kernel_launch(void* const* d_in, const int* in_sizes, int n_in,
                              void* d_out, int out_size, void* d_ws, size_t ws_size,
                              hipStream_t stream) {
    const float* x     = (const float*)d_in[0];
    const int*   erow  = (const int*)d_in[1];
    const int*   ecol  = (const int*)d_in[2];
    const float* eval_ = (const float*)d_in[3];
    const float* w     = (const float*)d_in[4];
    const float* b     = (const float*)d_in[5];
    float* out = (float*)d_out;

    const int M  = in_sizes[0] / K_FEATS;      // 100000
    const int E  = in_sizes[1];                // 1600000
    const int NB = (M + BROWS - 1) >> BSHIFT;  // 1563

    // workspace layout (16B aligned)
    size_t o_sup  = 0;                                               // bf16 sup
    size_t o_wt   = o_sup  + (((size_t)M * N_FEATS * 2 + 15) & ~15ul);
    size_t o_bcur = o_wt   + (size_t)K_FEATS * N_FEATS * 2;
    size_t o_tmp  = o_bcur + (((size_t)NB * 4 + 15) & ~15ul);

    unsigned short* sup  = (unsigned short*)((char*)d_ws + o_sup);
    unsigned short* wt   = (unsigned short*)((char*)d_ws + o_wt);
    int*            bcur = (int*)((char*)d_ws + o_bcur);
    int2*           tmp  = (int2*)((char*)d_ws + o_tmp);

    // dense path: W -> Wt bf16, sup = bf16(x @ W)
    prep_w<<<N_FEATS, 256, 0, stream>>>(w, wt);
    gcn_gemm_mfma<<<(M + 127) / 128, 256, 0, stream>>>(x, wt, sup, M);

    // sparse path: reservation-based bucket partition only (no row sort)
    zero_ints<<<(NB + 255) / 256, 256, 0, stream>>>(bcur, NB);
    int nchunks = (E + CHUNK - 1) / CHUNK;     // 196
    wg_partition<<<nchunks, 256, 0, stream>>>(erow, ecol, eval_, bcur, tmp, E, NB);

    // out[64-row tile] = LDS-accumulated sum(val * sup[col]) + b
    gcn_spmm_bucket<<<NB, 256, 0, stream>>>(bcur, tmp, (const unsigned int*)sup, b, out, M);
}

// Round 3
// 358.481 us; speedup vs baseline: 4.0074x; 4.0074x over previous
//
#include <hip/hip_runtime.h>

// GraphConvolution: out = segment_sum(edge_val * (x@W)[edge_col], edge_row) + b
// M=100000 nodes, K=256 in_feats, N=128 out_feats, E=1.6M edges. fp32 in/out.
//
// R5 (base, 389.9us): reservation-based bucket partition -> per-bucket row
// sort -> atomic-free wave-per-row spmm.
// R6/R7 FAILED: LDS fp32 atomicAdd compiles to a CAS loop without
// -munsafe-fp-atomics (VALUBusy 2.2%, 11x regression). Reverted.
// R8: spmm was latency-bound (HBM 29%, VALU 31%, ~2 gathers in flight/wave).
// New spmm: two 32-lane halves per wave, each lane = 4 feats (uint2 of bf16),
// each half a different edge, unrolled 4 -> 8 independent 256B gathers in
// flight per wave. Cross-half __shfl_xor(32) add, lanes 0-31 store float4.

#define K_FEATS 256
#define N_FEATS 128
#define BSHIFT 7                 // 128 rows per bucket
#define BROWS 128
#define BCAP 3072                // mean 2048, +22 sigma
#define CHUNK 8192
#define EPT 32                   // edges per thread (256 threads)

typedef __attribute__((ext_vector_type(8))) short short8;
typedef __attribute__((ext_vector_type(4))) float float4v;

__device__ __forceinline__ unsigned short f2bf(float f) {
    unsigned int u = __float_as_uint(f);
    unsigned int r = u + 0x7FFF + ((u >> 16) & 1);   // round-to-nearest-even
    return (unsigned short)(r >> 16);
}

// ---------------- prep: Wt[n][k] bf16 from w[k][n] fp32 ----------------
__global__ __launch_bounds__(256) void prep_w(const float* __restrict__ w,
                                              unsigned short* __restrict__ wt) {
    int n = blockIdx.x;
    int k = threadIdx.x;
    wt[n * K_FEATS + k] = f2bf(w[k * N_FEATS + n]);
}

// ---------------- GEMM: sup(bf16) = x @ W via MFMA ----------------
__global__ __launch_bounds__(256) void gcn_gemm_mfma(const float* __restrict__ x,
                                                     const unsigned short* __restrict__ wt,
                                                     unsigned short* __restrict__ sup, int M) {
    __shared__ __align__(16) unsigned short As[128 * 40];

    const int tid  = threadIdx.x;
    const int wv   = tid >> 6;
    const int lane = tid & 63;
    const int l15  = lane & 15;
    const int quad = lane >> 4;
    const int row0 = blockIdx.x * 128;

    float4v acc[2][8];
#pragma unroll
    for (int mt = 0; mt < 2; mt++)
#pragma unroll
        for (int nt = 0; nt < 8; nt++) acc[mt][nt] = (float4v)(0.f);

    for (int k0 = 0; k0 < K_FEATS; k0 += 32) {
#pragma unroll
        for (int l = 0; l < 4; l++) {
            int f   = tid + l * 256;
            int r   = f >> 3;
            int k4  = f & 7;
            int grow = row0 + r;
            float4 v = make_float4(0.f, 0.f, 0.f, 0.f);
            if (grow < M) v = *(const float4*)(x + (long)grow * K_FEATS + k0 + k4 * 4);
            unsigned int p0 = (unsigned int)f2bf(v.x) | ((unsigned int)f2bf(v.y) << 16);
            unsigned int p1 = (unsigned int)f2bf(v.z) | ((unsigned int)f2bf(v.w) << 16);
            *(uint2*)(&As[r * 40 + k4 * 4]) = make_uint2(p0, p1);
        }
        __syncthreads();

        short8 afrag[2];
#pragma unroll
        for (int mt = 0; mt < 2; mt++) {
            afrag[mt] = *(const short8*)(&As[(wv * 32 + mt * 16 + l15) * 40 + quad * 8]);
        }
        short8 bfrag[8];
#pragma unroll
        for (int nt = 0; nt < 8; nt++) {
            bfrag[nt] = *(const short8*)(wt + (nt * 16 + l15) * K_FEATS + k0 + quad * 8);
        }
#pragma unroll
        for (int mt = 0; mt < 2; mt++)
#pragma unroll
            for (int nt = 0; nt < 8; nt++)
                acc[mt][nt] = __builtin_amdgcn_mfma_f32_16x16x32_bf16(
                    afrag[mt], bfrag[nt], acc[mt][nt], 0, 0, 0);
        __syncthreads();
    }

#pragma unroll
    for (int mt = 0; mt < 2; mt++) {
#pragma unroll
        for (int reg = 0; reg < 4; reg++) {
            int grow = row0 + wv * 32 + mt * 16 + quad * 4 + reg;
            if (grow < M) {
#pragma unroll
                for (int nt = 0; nt < 8; nt++) {
                    sup[(long)grow * N_FEATS + nt * 16 + l15] = f2bf(acc[mt][nt][reg]);
                }
            }
        }
    }
}

// ---------------- bucket sort ----------------
__global__ __launch_bounds__(256) void zero_ints(int* __restrict__ p, int n) {
    int i = blockIdx.x * 256 + threadIdx.x;
    if (i < n) p[i] = 0;
}

// Phase 1: per-chunk LDS histogram -> one reservation atomic per (WG,bucket)
// -> write edges to reserved runs inside bucket-strided tmp regions.
__global__ __launch_bounds__(256) void wg_partition(const int* __restrict__ erow,
                                                    const int* __restrict__ ecol,
                                                    const float* __restrict__ eval_,
                                                    int* __restrict__ bcur,
                                                    int2* __restrict__ tmp, int E, int NB) {
    __shared__ int hist[1024];
    __shared__ int cur[1024];
    const int tid = threadIdx.x;
    const long e0 = (long)blockIdx.x * CHUNK;

    for (int i = tid; i < NB; i += 256) hist[i] = 0;
    __syncthreads();

    int rows[EPT];
#pragma unroll
    for (int i = 0; i < EPT; i++) {
        long e = e0 + tid + i * 256;
        int r = -1;
        if (e < E) {
            r = erow[e];
            atomicAdd(&hist[r >> BSHIFT], 1);
        }
        rows[i] = r;
    }
    __syncthreads();

    // one global reservation per touched bucket
    for (int i = tid; i < NB; i += 256) {
        int c = hist[i];
        cur[i] = c ? atomicAdd(&bcur[i], c) : 0;
    }
    __syncthreads();

    // place edges: LDS cursor gives offset within this WG's reserved run
#pragma unroll
    for (int i = 0; i < EPT; i++) {
        long e = e0 + tid + i * 256;
        if (e >= E) continue;
        int r = rows[i];
        int b = r >> BSHIFT;
        int p = atomicAdd(&cur[b], 1);
        if (p < BCAP)
            tmp[(long)b * BCAP + p] = make_int2(((r & (BROWS - 1)) << 17) | ecol[e],
                                                __float_as_int(eval_[e]));
    }
}

// exclusive scan of bucket counts (NB <= 1024), single block; off0[M] = total
__global__ __launch_bounds__(1024) void bucket_scan(const int* __restrict__ bcnt,
                                                    int* __restrict__ bbase,
                                                    int* __restrict__ off0,
                                                    int NB, int M) {
    __shared__ int sm[1024];
    int t = threadIdx.x;
    int v = 0;
    if (t < NB) { v = bcnt[t]; if (v > BCAP) v = BCAP; }
    sm[t] = v;
    __syncthreads();
#pragma unroll
    for (int s = 1; s < 1024; s <<= 1) {
        int a = (t >= s) ? sm[t - s] : 0;
        __syncthreads();
        sm[t] += a;
        __syncthreads();
    }
    if (t < NB) bbase[t] = sm[t] - v;
    if (t == 1023) off0[M] = sm[1023];
}

// one block per bucket: LDS histogram + scan of its 128 rows -> off0,
// then place edges into contiguous sorted window of sedge.
__global__ __launch_bounds__(256) void bucket_to_sorted(const int* __restrict__ bcnt,
                                                        const int* __restrict__ bbase,
                                                        const int2* __restrict__ tmp,
                                                        int* __restrict__ off0,
                                                        int2* __restrict__ sedge, int M) {
    __shared__ int hist[BROWS];
    __shared__ int cur[BROWS];
    const int b   = blockIdx.x;
    const int tid = threadIdx.x;
    const int row0 = b << BSHIFT;

    if (tid < BROWS) hist[tid] = 0;
    __syncthreads();

    int cnt = bcnt[b];
    if (cnt > BCAP) cnt = BCAP;
    const int2* t = tmp + (long)b * BCAP;

    for (int i = tid; i < cnt; i += 256)
        atomicAdd(&hist[(unsigned)t[i].x >> 17], 1);
    __syncthreads();

    if (tid < BROWS) cur[tid] = hist[tid];
    __syncthreads();
#pragma unroll
    for (int s = 1; s < BROWS; s <<= 1) {
        int v = 0;
        if (tid >= s && tid < BROWS) v = cur[tid - s];
        __syncthreads();
        if (tid < BROWS) cur[tid] += v;
        __syncthreads();
    }

    const int base = bbase[b];
    if (tid < BROWS) {
        int start = base + cur[tid] - hist[tid];   // exclusive
        cur[tid] = start;
        if (row0 + tid < M) off0[row0 + tid] = start;
    }
    __syncthreads();

    for (int i = tid; i < cnt; i += 256) {
        int2 e = t[i];
        int rl = (unsigned)e.x >> 17;
        int p = atomicAdd(&cur[rl], 1);
        sedge[p] = make_int2(e.x & 0x1FFFF, e.y);
    }
}

// ---------------- SpMM: wave per row, split-wave edge pairs, no atomics ------
// Two 32-lane halves; each lane = 4 feats (uint2 = 4 bf16); half h processes
// edges at offset s+h, s+h+2, ... Unroll 4 -> 8 gathers in flight per wave.
__global__ __launch_bounds__(256) void gcn_spmm(const int* __restrict__ off0,
                                                const int2* __restrict__ sedge,
                                                const unsigned short* __restrict__ sup,
                                                const float* __restrict__ b,
                                                float* __restrict__ out, int M) {
    int row  = blockIdx.x * 4 + (threadIdx.x >> 6);
    if (row >= M) return;
    int lane = threadIdx.x & 63;
    int half = lane >> 5;
    int l31  = lane & 31;
    int s = off0[row], e = off0[row + 1];
    const uint2* sup64 = (const uint2*)sup;   // 4 bf16 per uint2

    float4v acc = (float4v)(0.f);
    int base = s;
    for (; base + 8 <= e; base += 8) {
        int2 ed[4];
#pragma unroll
        for (int u = 0; u < 4; u++) ed[u] = sedge[base + half + 2 * u];
        uint2 g[4];
#pragma unroll
        for (int u = 0; u < 4; u++) g[u] = sup64[(long)ed[u].x * 32 + l31];
#pragma unroll
        for (int u = 0; u < 4; u++) {
            float v = __int_as_float(ed[u].y);
            acc.x += v * __uint_as_float(g[u].x << 16);
            acc.y += v * __uint_as_float(g[u].x & 0xFFFF0000u);
            acc.z += v * __uint_as_float(g[u].y << 16);
            acc.w += v * __uint_as_float(g[u].y & 0xFFFF0000u);
        }
    }
    for (int i = base + half; i < e; i += 2) {
        int2 ed = sedge[i];
        uint2 g = sup64[(long)ed.x * 32 + l31];
        float v = __int_as_float(ed.y);
        acc.x += v * __uint_as_float(g.x << 16);
        acc.y += v * __uint_as_float(g.x & 0xFFFF0000u);
        acc.z += v * __uint_as_float(g.y << 16);
        acc.w += v * __uint_as_float(g.y & 0xFFFF0000u);
    }

    // cross-half reduce: half 1's partials fold into half 0
    acc.x += __shfl_xor(acc.x, 32);
    acc.y += __shfl_xor(acc.y, 32);
    acc.z += __shfl_xor(acc.z, 32);
    acc.w += __shfl_xor(acc.w, 32);

    if (half == 0) {
        float4v bb = ((const float4v*)b)[l31];
        acc += bb;
        *(float4v*)(out + (long)row * N_FEATS + l31 * 4) = acc;
    }
}

extern "C" void kernel_launch(void* const* d_in, const int* in_sizes, int n_in,
                              void* d_out, int out_size, void* d_ws, size_t ws_size,
                              hipStream_t stream) {
    const float* x     = (const float*)d_in[0];
    const int*   erow  = (const int*)d_in[1];
    const int*   ecol  = (const int*)d_in[2];
    const float* eval_ = (const float*)d_in[3];
    const float* w     = (const float*)d_in[4];
    const float* b     = (const float*)d_in[5];
    float* out = (float*)d_out;

    const int M  = in_sizes[0] / K_FEATS;      // 100000
    const int E  = in_sizes[1];                // 1600000
    const int NB = (M + BROWS - 1) >> BSHIFT;  // 782

    // workspace layout (16B aligned)
    size_t o_sup   = 0;                                               // bf16 sup
    size_t o_wt    = o_sup   + (((size_t)M * N_FEATS * 2 + 15) & ~15ul);
    size_t o_off0  = o_wt    + (size_t)K_FEATS * N_FEATS * 2;
    size_t o_bcur  = o_off0  + (((size_t)(M + 1) * 4 + 15) & ~15ul);
    size_t o_bbase = o_bcur  + (((size_t)NB * 4 + 15) & ~15ul);
    size_t o_tmp   = o_bbase + (((size_t)NB * 4 + 15) & ~15ul);
    size_t o_edge  = o_tmp   + ((size_t)NB * BCAP * 8);

    unsigned short* sup   = (unsigned short*)((char*)d_ws + o_sup);
    unsigned short* wt    = (unsigned short*)((char*)d_ws + o_wt);
    int*            off0  = (int*)((char*)d_ws + o_off0);
    int*            bcur  = (int*)((char*)d_ws + o_bcur);
    int*            bbase = (int*)((char*)d_ws + o_bbase);
    int2*           tmp   = (int2*)((char*)d_ws + o_tmp);
    int2*           sedge = (int2*)((char*)d_ws + o_edge);

    // dense path: W -> Wt bf16, sup = bf16(x @ W)
    prep_w<<<N_FEATS, 256, 0, stream>>>(w, wt);
    gcn_gemm_mfma<<<(M + 127) / 128, 256, 0, stream>>>(x, wt, sup, M);

    // sparse path: reservation-based bucket partition, then per-bucket sort
    zero_ints<<<(NB + 255) / 256, 256, 0, stream>>>(bcur, NB);
    int nchunks = (E + CHUNK - 1) / CHUNK;     // 196
    wg_partition<<<nchunks, 256, 0, stream>>>(erow, ecol, eval_, bcur, tmp, E, NB);
    bucket_scan<<<1, 1024, 0, stream>>>(bcur, bbase, off0, NB, M);
    bucket_to_sorted<<<NB, 256, 0, stream>>>(bcur, bbase, tmp, off0, sedge, M);

    // out[row] = sum(val * sup[col]) + b
    gcn_spmm<<<(M + 3) / 4, 256, 0, stream>>>(off0, sedge, sup, b, out, M);
}

// Round 4
// 329.301 us; speedup vs baseline: 4.3625x; 1.0886x over previous
//
#include <hip/hip_runtime.h>

// GraphConvolution: out = segment_sum(edge_val * (x@W)[edge_col], edge_row) + b
// M=100000 nodes, K=256 in_feats, N=128 out_feats, E=1.6M edges. fp32 in/out.
//
// R5 (389.9us): bucket partition -> per-bucket row sort -> atomic-free spmm.
// R8 (358.5us): split-wave spmm (8 gathers in flight/wave), spmm ~70us.
// R9: gemm was 87us at MfmaUtil 2.8% / VALU 6% / occ 20% -- latency-bound on
// its own barriers. The LDS A-tile was per-wave-exclusive, so staging+2
// barriers per K-step bought nothing. Now: barrier-free gemm (direct global
// A-fragment loads + in-register f2bf; B from L1-hot wt), FUSED with
// wg_partition in one dispatch (roles interleaved mod-5) so the memory/atomic
// partition hides under the MFMA/latency gemm.

#define K_FEATS 256
#define N_FEATS 128
#define BSHIFT 7                 // 128 rows per bucket
#define BROWS 128
#define BCAP 3072                // mean 2048, +22 sigma
#define CHUNK 8192
#define EPT 32                   // edges per thread (256 threads)
#define RMOD 5                   // 1 of every RMOD blocks is a partition block

typedef __attribute__((ext_vector_type(8))) short short8;
typedef __attribute__((ext_vector_type(4))) float float4v;

__device__ __forceinline__ unsigned short f2bf(float f) {
    unsigned int u = __float_as_uint(f);
    unsigned int r = u + 0x7FFF + ((u >> 16) & 1);   // round-to-nearest-even
    return (unsigned short)(r >> 16);
}

// ---------------- prep: Wt[n][k] bf16 from w[k][n] fp32 ----------------
__global__ __launch_bounds__(256) void prep_w(const float* __restrict__ w,
                                              unsigned short* __restrict__ wt) {
    int n = blockIdx.x;
    int k = threadIdx.x;
    wt[n * K_FEATS + k] = f2bf(w[k * N_FEATS + n]);
}

__global__ __launch_bounds__(256) void zero_ints(int* __restrict__ p, int n) {
    int i = blockIdx.x * 256 + threadIdx.x;
    if (i < n) p[i] = 0;
}

// ---------------- fused: barrier-free GEMM + edge partition ----------------
// blockIdx % RMOD == 0 -> partition chunk; else gemm tile (128 rows).
__global__ __launch_bounds__(256) void gemm_partition(
        const float* __restrict__ x, const unsigned short* __restrict__ wt,
        unsigned short* __restrict__ sup, int M, int NT,
        const int* __restrict__ erow, const int* __restrict__ ecol,
        const float* __restrict__ eval_, int* __restrict__ bcur,
        int2* __restrict__ tmp, int E, int NB, int NCH) {
    __shared__ int hist[1024];
    __shared__ int cur[1024];
    const int g   = blockIdx.x;
    const int tid = threadIdx.x;

    if (g % RMOD == 0) {
        // ---------- partition role ----------
        int pid = g / RMOD;
        if (pid >= NCH) return;
        const long e0 = (long)pid * CHUNK;

        for (int i = tid; i < NB; i += 256) hist[i] = 0;
        __syncthreads();

        int rows[EPT];
#pragma unroll
        for (int i = 0; i < EPT; i++) {
            long e = e0 + tid + i * 256;
            int r = -1;
            if (e < E) {
                r = erow[e];
                atomicAdd(&hist[r >> BSHIFT], 1);
            }
            rows[i] = r;
        }
        __syncthreads();

        // one global reservation per touched bucket
        for (int i = tid; i < NB; i += 256) {
            int c = hist[i];
            cur[i] = c ? atomicAdd(&bcur[i], c) : 0;
        }
        __syncthreads();

        // place edges: LDS cursor gives offset within this WG's reserved run
#pragma unroll
        for (int i = 0; i < EPT; i++) {
            long e = e0 + tid + i * 256;
            if (e >= E) continue;
            int r = rows[i];
            int b = r >> BSHIFT;
            int p = atomicAdd(&cur[b], 1);
            if (p < BCAP)
                tmp[(long)b * BCAP + p] = make_int2(((r & (BROWS - 1)) << 17) | ecol[e],
                                                    __float_as_int(eval_[e]));
        }
        return;
    }

    // ---------- gemm role: barrier-free, per-wave-exclusive A ----------
    int tile = g - g / RMOD - 1;
    if (tile >= NT) return;

    const int wv   = tid >> 6;
    const int lane = tid & 63;
    const int l15  = lane & 15;
    const int quad = lane >> 4;
    const int row0 = tile * 128 + wv * 32;   // this wave's 32 rows

    float4v acc[2][8];
#pragma unroll
    for (int mt = 0; mt < 2; mt++)
#pragma unroll
        for (int nt = 0; nt < 8; nt++) acc[mt][nt] = (float4v)(0.f);

#pragma unroll 2
    for (int k0 = 0; k0 < K_FEATS; k0 += 32) {
        short8 afrag[2];
#pragma unroll
        for (int mt = 0; mt < 2; mt++) {
            int grow = row0 + mt * 16 + l15;
            float4 a0 = make_float4(0.f, 0.f, 0.f, 0.f);
            float4 a1 = make_float4(0.f, 0.f, 0.f, 0.f);
            if (grow < M) {
                const float* p = x + (long)grow * K_FEATS + k0 + quad * 8;
                a0 = *(const float4*)p;
                a1 = *(const float4*)(p + 4);
            }
            short8 af;
            af[0] = (short)f2bf(a0.x); af[1] = (short)f2bf(a0.y);
            af[2] = (short)f2bf(a0.z); af[3] = (short)f2bf(a0.w);
            af[4] = (short)f2bf(a1.x); af[5] = (short)f2bf(a1.y);
            af[6] = (short)f2bf(a1.z); af[7] = (short)f2bf(a1.w);
            afrag[mt] = af;
        }
        short8 bfrag[8];
#pragma unroll
        for (int nt = 0; nt < 8; nt++) {
            bfrag[nt] = *(const short8*)(wt + (nt * 16 + l15) * K_FEATS + k0 + quad * 8);
        }
#pragma unroll
        for (int mt = 0; mt < 2; mt++)
#pragma unroll
            for (int nt = 0; nt < 8; nt++)
                acc[mt][nt] = __builtin_amdgcn_mfma_f32_16x16x32_bf16(
                    afrag[mt], bfrag[nt], acc[mt][nt], 0, 0, 0);
    }

#pragma unroll
    for (int mt = 0; mt < 2; mt++) {
#pragma unroll
        for (int reg = 0; reg < 4; reg++) {
            int grow = row0 + mt * 16 + quad * 4 + reg;
            if (grow < M) {
#pragma unroll
                for (int nt = 0; nt < 8; nt++) {
                    sup[(long)grow * N_FEATS + nt * 16 + l15] = f2bf(acc[mt][nt][reg]);
                }
            }
        }
    }
}

// exclusive scan of bucket counts (NB <= 1024), single block; off0[M] = total
__global__ __launch_bounds__(1024) void bucket_scan(const int* __restrict__ bcnt,
                                                    int* __restrict__ bbase,
                                                    int* __restrict__ off0,
                                                    int NB, int M) {
    __shared__ int sm[1024];
    int t = threadIdx.x;
    int v = 0;
    if (t < NB) { v = bcnt[t]; if (v > BCAP) v = BCAP; }
    sm[t] = v;
    __syncthreads();
#pragma unroll
    for (int s = 1; s < 1024; s <<= 1) {
        int a = (t >= s) ? sm[t - s] : 0;
        __syncthreads();
        sm[t] += a;
        __syncthreads();
    }
    if (t < NB) bbase[t] = sm[t] - v;
    if (t == 1023) off0[M] = sm[1023];
}

// one block per bucket: LDS histogram + scan of its 128 rows -> off0,
// then place edges into contiguous sorted window of sedge.
__global__ __launch_bounds__(256) void bucket_to_sorted(const int* __restrict__ bcnt,
                                                        const int* __restrict__ bbase,
                                                        const int2* __restrict__ tmp,
                                                        int* __restrict__ off0,
                                                        int2* __restrict__ sedge, int M) {
    __shared__ int hist[BROWS];
    __shared__ int cur[BROWS];
    const int b   = blockIdx.x;
    const int tid = threadIdx.x;
    const int row0 = b << BSHIFT;

    if (tid < BROWS) hist[tid] = 0;
    __syncthreads();

    int cnt = bcnt[b];
    if (cnt > BCAP) cnt = BCAP;
    const int2* t = tmp + (long)b * BCAP;

    for (int i = tid; i < cnt; i += 256)
        atomicAdd(&hist[(unsigned)t[i].x >> 17], 1);
    __syncthreads();

    if (tid < BROWS) cur[tid] = hist[tid];
    __syncthreads();
#pragma unroll
    for (int s = 1; s < BROWS; s <<= 1) {
        int v = 0;
        if (tid >= s && tid < BROWS) v = cur[tid - s];
        __syncthreads();
        if (tid < BROWS) cur[tid] += v;
        __syncthreads();
    }

    const int base = bbase[b];
    if (tid < BROWS) {
        int start = base + cur[tid] - hist[tid];   // exclusive
        cur[tid] = start;
        if (row0 + tid < M) off0[row0 + tid] = start;
    }
    __syncthreads();

    for (int i = tid; i < cnt; i += 256) {
        int2 e = t[i];
        int rl = (unsigned)e.x >> 17;
        int p = atomicAdd(&cur[rl], 1);
        sedge[p] = make_int2(e.x & 0x1FFFF, e.y);
    }
}

// ---------------- SpMM: wave per row, split-wave edge pairs, no atomics ------
// Two 32-lane halves; each lane = 4 feats (uint2 = 4 bf16); half h processes
// edges at offset s+h, s+h+2, ... Unroll 4 -> 8 gathers in flight per wave.
__global__ __launch_bounds__(256) void gcn_spmm(const int* __restrict__ off0,
                                                const int2* __restrict__ sedge,
                                                const unsigned short* __restrict__ sup,
                                                const float* __restrict__ b,
                                                float* __restrict__ out, int M) {
    int row  = blockIdx.x * 4 + (threadIdx.x >> 6);
    if (row >= M) return;
    int lane = threadIdx.x & 63;
    int half = lane >> 5;
    int l31  = lane & 31;
    int s = off0[row], e = off0[row + 1];
    const uint2* sup64 = (const uint2*)sup;   // 4 bf16 per uint2

    float4v acc = (float4v)(0.f);
    int base = s;
    for (; base + 8 <= e; base += 8) {
        int2 ed[4];
#pragma unroll
        for (int u = 0; u < 4; u++) ed[u] = sedge[base + half + 2 * u];
        uint2 g[4];
#pragma unroll
        for (int u = 0; u < 4; u++) g[u] = sup64[(long)ed[u].x * 32 + l31];
#pragma unroll
        for (int u = 0; u < 4; u++) {
            float v = __int_as_float(ed[u].y);
            acc.x += v * __uint_as_float(g[u].x << 16);
            acc.y += v * __uint_as_float(g[u].x & 0xFFFF0000u);
            acc.z += v * __uint_as_float(g[u].y << 16);
            acc.w += v * __uint_as_float(g[u].y & 0xFFFF0000u);
        }
    }
    for (int i = base + half; i < e; i += 2) {
        int2 ed = sedge[i];
        uint2 g = sup64[(long)ed.x * 32 + l31];
        float v = __int_as_float(ed.y);
        acc.x += v * __uint_as_float(g.x << 16);
        acc.y += v * __uint_as_float(g.x & 0xFFFF0000u);
        acc.z += v * __uint_as_float(g.y << 16);
        acc.w += v * __uint_as_float(g.y & 0xFFFF0000u);
    }

    // cross-half reduce: half 1's partials fold into half 0
    acc.x += __shfl_xor(acc.x, 32);
    acc.y += __shfl_xor(acc.y, 32);
    acc.z += __shfl_xor(acc.z, 32);
    acc.w += __shfl_xor(acc.w, 32);

    if (half == 0) {
        float4v bb = ((const float4v*)b)[l31];
        acc += bb;
        *(float4v*)(out + (long)row * N_FEATS + l31 * 4) = acc;
    }
}

extern "C" void kernel_launch(void* const* d_in, const int* in_sizes, int n_in,
                              void* d_out, int out_size, void* d_ws, size_t ws_size,
                              hipStream_t stream) {
    const float* x     = (const float*)d_in[0];
    const int*   erow  = (const int*)d_in[1];
    const int*   ecol  = (const int*)d_in[2];
    const float* eval_ = (const float*)d_in[3];
    const float* w     = (const float*)d_in[4];
    const float* b     = (const float*)d_in[5];
    float* out = (float*)d_out;

    const int M  = in_sizes[0] / K_FEATS;      // 100000
    const int E  = in_sizes[1];                // 1600000
    const int NB = (M + BROWS - 1) >> BSHIFT;  // 782
    const int NT = (M + 127) / 128;            // 782 gemm tiles
    const int NCH = (E + CHUNK - 1) / CHUNK;   // 196 partition chunks

    // workspace layout (16B aligned)
    size_t o_sup   = 0;                                               // bf16 sup
    size_t o_wt    = o_sup   + (((size_t)M * N_FEATS * 2 + 15) & ~15ul);
    size_t o_off0  = o_wt    + (size_t)K_FEATS * N_FEATS * 2;
    size_t o_bcur  = o_off0  + (((size_t)(M + 1) * 4 + 15) & ~15ul);
    size_t o_bbase = o_bcur  + (((size_t)NB * 4 + 15) & ~15ul);
    size_t o_tmp   = o_bbase + (((size_t)NB * 4 + 15) & ~15ul);
    size_t o_edge  = o_tmp   + ((size_t)NB * BCAP * 8);

    unsigned short* sup   = (unsigned short*)((char*)d_ws + o_sup);
    unsigned short* wt    = (unsigned short*)((char*)d_ws + o_wt);
    int*            off0  = (int*)((char*)d_ws + o_off0);
    int*            bcur  = (int*)((char*)d_ws + o_bcur);
    int*            bbase = (int*)((char*)d_ws + o_bbase);
    int2*           tmp   = (int2*)((char*)d_ws + o_tmp);
    int2*           sedge = (int2*)((char*)d_ws + o_edge);

    prep_w<<<N_FEATS, 256, 0, stream>>>(w, wt);
    zero_ints<<<(NB + 255) / 256, 256, 0, stream>>>(bcur, NB);

    // fused dense GEMM + sparse partition (independent until spmm)
    int nblk = NT + NCH;                       // mod-RMOD interleave covers both
    gemm_partition<<<nblk, 256, 0, stream>>>(x, wt, sup, M, NT,
                                             erow, ecol, eval_, bcur, tmp, E, NB, NCH);

    bucket_scan<<<1, 1024, 0, stream>>>(bcur, bbase, off0, NB, M);
    bucket_to_sorted<<<NB, 256, 0, stream>>>(bcur, bbase, tmp, off0, sedge, M);

    // out[row] = sum(val * sup[col]) + b
    gcn_spmm<<<(M + 3) / 4, 256, 0, stream>>>(off0, sedge, sup, b, out, M);
}